// Round 1
// baseline (2192.781 us; speedup 1.0000x reference)
//
#include <hip/hip_runtime.h>

// MaxUnpooling2D scatter-add (replicates the TF batch-offset bug:
// batch offset uses flat INPUT size = 128*128*256 = 2^22).
//
// updates: (8,128,128,256) fp32, 33,554,432 elems
// mask:    same shape int32, values in [0, 16,777,216)
// out:     (8,256,256,256) fp32, 134,217,728 elems
//
// out[mask[i] + (i>>22)<<22] += updates[i];  rest of out = 0.

constexpr int FLAT_IN = 128 * 128 * 256;  // 4,194,304 = 2^22

__global__ __launch_bounds__(256) void scatter_add4_kernel(
    const float4* __restrict__ upd4,
    const int4* __restrict__ msk4,
    float* __restrict__ out,
    int n4) {
  int j = blockIdx.x * blockDim.x + threadIdx.x;
  if (j >= n4) return;

  float4 u = upd4[j];
  int4 m = msk4[j];
  // All 4 elements (indices 4j..4j+3) share one batch: FLAT_IN % 4 == 0.
  int base = (j * 4) & ~(FLAT_IN - 1);  // batch * FLAT_IN

  // unsafeAtomicAdd -> hardware global_atomic_add_f32 (no CAS loop).
  unsafeAtomicAdd(out + (base + m.x), u.x);
  unsafeAtomicAdd(out + (base + m.y), u.y);
  unsafeAtomicAdd(out + (base + m.z), u.z);
  unsafeAtomicAdd(out + (base + m.w), u.w);
}

extern "C" void kernel_launch(void* const* d_in, const int* in_sizes, int n_in,
                              void* d_out, int out_size, void* d_ws, size_t ws_size,
                              hipStream_t stream) {
  const float* updates = (const float*)d_in[0];
  const int*   mask    = (const int*)d_in[1];
  float*       out     = (float*)d_out;
  int n = in_sizes[0];  // 33,554,432 (multiple of 4)

  // Output is poisoned 0xAA before every call — zero it first.
  hipMemsetAsync(d_out, 0, (size_t)out_size * sizeof(float), stream);

  int n4 = n / 4;
  int block = 256;
  int grid = (n4 + block - 1) / block;
  scatter_add4_kernel<<<grid, block, 0, stream>>>(
      (const float4*)updates, (const int4*)mask, out, n4);
}

// Round 2
// 1300.146 us; speedup vs baseline: 1.6866x; 1.6866x over previous
//
#include <hip/hip_runtime.h>

// MaxUnpooling2D scatter-add, bucketed radix-partition version.
//
// out[mask[i] + (i & ~(FLAT_IN-1))] += updates[i];  rest of out = 0.
// Touched window: [0, OUT_WIN), OUT_WIN = 7*2^22 + 2^24 = 46,137,344.
//
// R1 showed 33.5M random global fp32 atomics run at only ~21 G/s
// (transaction-rate wall at the coherence point, 750 GB/s, VALU idle).
// This version sorts (idx,val) pairs by 16K-float output bucket, then
// applies each bucket with LDS atomics + one coalesced 64KB store.

constexpr int FLAT_IN     = 1 << 22;              // 4,194,304
constexpr int N_ELEMS     = 8 * FLAT_IN;          // 33,554,432
constexpr int OUT_WIN     = 7 * FLAT_IN + (1 << 24); // 46,137,344
constexpr int OUT_TOTAL   = 134217728;
constexpr int BKT_SHIFT   = 14;
constexpr int BKT_SIZE    = 1 << BKT_SHIFT;       // 16,384 floats = 64 KB
constexpr int NB          = OUT_WIN >> BKT_SHIFT; // 2816 = 11*256
constexpr int CHUNK       = 16384;                // elems per partition block
constexpr int NBLK        = N_ELEMS / CHUNK;      // 2048
constexpr int SEGS        = 16;
constexpr int SEG_ROWS    = NBLK / SEGS;          // 128

// ---- workspace layout (bytes) ----
// pairs  : int2[N_ELEMS]            @ 0          (268,435,456)
// hist   : int[NBLK*NB]             @ 268,435,456 (23,068,672)
// segsum : int[SEGS*NB]             @ 291,504,128 (180,224)
// bbase  : int[NB+1]                @ 291,684,352 (11,268)
constexpr size_t WS_PAIRS  = 0;
constexpr size_t WS_HIST   = 268435456;
constexpr size_t WS_SEGSUM = WS_HIST + (size_t)NBLK * NB * 4;
constexpr size_t WS_BBASE  = WS_SEGSUM + (size_t)SEGS * NB * 4;
constexpr size_t WS_NEEDED = WS_BBASE + (size_t)(NB + 1) * 4;

// ---------------- K0: zero a float4 range ----------------
__global__ __launch_bounds__(256) void zero_kernel(float4* __restrict__ p, int n4) {
  int i = blockIdx.x * 256 + threadIdx.x;
  int stride = gridDim.x * 256;
  for (; i < n4; i += stride) p[i] = make_float4(0.f, 0.f, 0.f, 0.f);
}

// ---------------- K1: per-block bucket histogram ----------------
__global__ __launch_bounds__(256) void p1_hist(const int4* __restrict__ mask4,
                                               int* __restrict__ hist) {
  __shared__ int cnt[NB];
  const int blk = blockIdx.x, tid = threadIdx.x;
  for (int j = tid; j < NB; j += 256) cnt[j] = 0;
  __syncthreads();
  const int base4 = blk * (CHUNK / 4);
  #pragma unroll
  for (int k = 0; k < CHUNK / 1024; ++k) {   // 16 iters
    int j4 = base4 + k * 256 + tid;
    int4 m = mask4[j4];
    int boff = (j4 * 4) & ~(FLAT_IN - 1);    // batch offset, same for all 4
    atomicAdd(&cnt[(m.x + boff) >> BKT_SHIFT], 1);
    atomicAdd(&cnt[(m.y + boff) >> BKT_SHIFT], 1);
    atomicAdd(&cnt[(m.z + boff) >> BKT_SHIFT], 1);
    atomicAdd(&cnt[(m.w + boff) >> BKT_SHIFT], 1);
  }
  __syncthreads();
  for (int j = tid; j < NB; j += 256) hist[blk * NB + j] = cnt[j];
}

// ---------------- K2a: segment sums over block rows ----------------
// grid = (11, SEGS); thread -> bucket b, blockIdx.y -> segment
__global__ __launch_bounds__(256) void p2_segsum(const int* __restrict__ hist,
                                                 int* __restrict__ segsum) {
  int b = blockIdx.x * 256 + threadIdx.x;
  int seg = blockIdx.y;
  const int* p = hist + (size_t)(seg * SEG_ROWS) * NB + b;
  int s = 0;
  #pragma unroll 4
  for (int k = 0; k < SEG_ROWS; ++k) s += p[(size_t)k * NB];
  segsum[seg * NB + b] = s;
}

// ---------------- K2b: bucket totals + exclusive scan -> bbase ----------------
__global__ __launch_bounds__(256) void p2_scan(const int* __restrict__ segsum,
                                               int* __restrict__ bbase) {
  __shared__ int tot[NB];
  __shared__ int partial[256];
  const int t = threadIdx.x;
  for (int j = t; j < NB; j += 256) {
    int s = 0;
    #pragma unroll
    for (int g = 0; g < SEGS; ++g) s += segsum[g * NB + j];
    tot[j] = s;
  }
  __syncthreads();
  int local = 0;
  #pragma unroll
  for (int k = 0; k < NB / 256; ++k) local += tot[t * (NB / 256) + k];
  partial[t] = local;
  __syncthreads();
  // inclusive Hillis-Steele scan over 256 partials
  for (int off = 1; off < 256; off <<= 1) {
    int tmp = (t >= off) ? partial[t - off] : 0;
    __syncthreads();
    partial[t] += tmp;
    __syncthreads();
  }
  int run = partial[t] - local;  // exclusive base for this thread's chunk
  #pragma unroll
  for (int k = 0; k < NB / 256; ++k) {
    int b = t * (NB / 256) + k;
    bbase[b] = run;
    run += tot[b];
  }
  if (t == 255) bbase[NB] = run;  // == N_ELEMS
}

// ---------------- K2c: expand hist in place to within-bucket offsets ----------------
__global__ __launch_bounds__(256) void p2_expand(int* __restrict__ hist,
                                                 const int* __restrict__ segsum) {
  int b = blockIdx.x * 256 + threadIdx.x;
  int seg = blockIdx.y;
  int run = 0;
  for (int g = 0; g < seg; ++g) run += segsum[g * NB + b];
  int* p = hist + (size_t)(seg * SEG_ROWS) * NB + b;
  for (int k = 0; k < SEG_ROWS; ++k) {
    int v = p[(size_t)k * NB];
    p[(size_t)k * NB] = run;
    run += v;
  }
}

// ---------------- K3: place pairs into bucket-sorted order ----------------
__global__ __launch_bounds__(256) void p3_place(const int4* __restrict__ mask4,
                                                const float4* __restrict__ upd4,
                                                const int* __restrict__ hist,
                                                const int* __restrict__ bbase,
                                                int2* __restrict__ pairs) {
  __shared__ int cnt[NB];
  __shared__ int rowbase[NB];  // absolute start for this (block,bucket)
  const int blk = blockIdx.x, tid = threadIdx.x;
  for (int j = tid; j < NB; j += 256) {
    cnt[j] = 0;
    rowbase[j] = bbase[j] + hist[blk * NB + j];
  }
  __syncthreads();
  const int base4 = blk * (CHUNK / 4);
  #pragma unroll
  for (int k = 0; k < CHUNK / 1024; ++k) {   // 16 iters
    int j4 = base4 + k * 256 + tid;
    int4 m = mask4[j4];
    float4 u = upd4[j4];
    int boff = (j4 * 4) & ~(FLAT_IN - 1);
    {
      int idx = m.x + boff; int b = idx >> BKT_SHIFT;
      int r = atomicAdd(&cnt[b], 1);
      pairs[rowbase[b] + r] = make_int2(idx, __float_as_int(u.x));
    }
    {
      int idx = m.y + boff; int b = idx >> BKT_SHIFT;
      int r = atomicAdd(&cnt[b], 1);
      pairs[rowbase[b] + r] = make_int2(idx, __float_as_int(u.y));
    }
    {
      int idx = m.z + boff; int b = idx >> BKT_SHIFT;
      int r = atomicAdd(&cnt[b], 1);
      pairs[rowbase[b] + r] = make_int2(idx, __float_as_int(u.z));
    }
    {
      int idx = m.w + boff; int b = idx >> BKT_SHIFT;
      int r = atomicAdd(&cnt[b], 1);
      pairs[rowbase[b] + r] = make_int2(idx, __float_as_int(u.w));
    }
  }
}

// ---------------- K4: apply one bucket via LDS, store window ----------------
__global__ __launch_bounds__(256) void p4_apply(const int2* __restrict__ pairs,
                                                const int* __restrict__ bbase,
                                                float* __restrict__ out) {
  __shared__ float win[BKT_SIZE];  // 64 KB
  const int bkt = blockIdx.x, tid = threadIdx.x;
  float4* w4 = (float4*)win;
  #pragma unroll
  for (int k = 0; k < BKT_SIZE / 1024; ++k)
    w4[k * 256 + tid] = make_float4(0.f, 0.f, 0.f, 0.f);
  __syncthreads();
  const int s = bbase[bkt], e = bbase[bkt + 1];
  for (int i = s + tid; i < e; i += 256) {
    int2 p = pairs[i];
    atomicAdd(&win[p.x & (BKT_SIZE - 1)], __int_as_float(p.y));  // ds_add_f32
  }
  __syncthreads();
  float4* o4 = (float4*)(out + (size_t)bkt * BKT_SIZE);
  #pragma unroll
  for (int k = 0; k < BKT_SIZE / 1024; ++k)
    o4[k * 256 + tid] = w4[k * 256 + tid];
}

// ---------------- fallback: R1 atomic scatter ----------------
__global__ __launch_bounds__(256) void scatter_add4_kernel(
    const float4* __restrict__ upd4, const int4* __restrict__ msk4,
    float* __restrict__ out, int n4) {
  int j = blockIdx.x * blockDim.x + threadIdx.x;
  if (j >= n4) return;
  float4 u = upd4[j];
  int4 m = msk4[j];
  int base = (j * 4) & ~(FLAT_IN - 1);
  unsafeAtomicAdd(out + (base + m.x), u.x);
  unsafeAtomicAdd(out + (base + m.y), u.y);
  unsafeAtomicAdd(out + (base + m.z), u.z);
  unsafeAtomicAdd(out + (base + m.w), u.w);
}

extern "C" void kernel_launch(void* const* d_in, const int* in_sizes, int n_in,
                              void* d_out, int out_size, void* d_ws, size_t ws_size,
                              hipStream_t stream) {
  const float* updates = (const float*)d_in[0];
  const int*   mask    = (const int*)d_in[1];
  float*       out     = (float*)d_out;
  const int n = in_sizes[0];

  const bool fast = (n == N_ELEMS) && (out_size == OUT_TOTAL) && (ws_size >= WS_NEEDED);

  if (!fast) {
    // fallback: full zero + global atomic scatter
    int n4z = out_size / 4;
    zero_kernel<<<(n4z + 2047) / 2048, 256, 0, stream>>>((float4*)d_out, n4z);
    int n4 = n / 4;
    scatter_add4_kernel<<<(n4 + 255) / 256, 256, 0, stream>>>(
        (const float4*)updates, (const int4*)mask, out, n4);
    return;
  }

  char* ws = (char*)d_ws;
  int2* pairs  = (int2*)(ws + WS_PAIRS);
  int*  hist   = (int*)(ws + WS_HIST);
  int*  segsum = (int*)(ws + WS_SEGSUM);
  int*  bbase  = (int*)(ws + WS_BBASE);

  // zero the untouched tail of out: [OUT_WIN, OUT_TOTAL)
  {
    int n4 = (OUT_TOTAL - OUT_WIN) / 4;  // 22,020,096
    zero_kernel<<<10752, 256, 0, stream>>>((float4*)(out + OUT_WIN), n4);
  }
  p1_hist<<<NBLK, 256, 0, stream>>>((const int4*)mask, hist);
  p2_segsum<<<dim3(NB / 256, SEGS), 256, 0, stream>>>(hist, segsum);
  p2_scan<<<1, 256, 0, stream>>>(segsum, bbase);
  p2_expand<<<dim3(NB / 256, SEGS), 256, 0, stream>>>(hist, segsum);
  p3_place<<<NBLK, 256, 0, stream>>>((const int4*)mask, (const float4*)updates,
                                     hist, bbase, pairs);
  p4_apply<<<NB, 256, 0, stream>>>(pairs, bbase, out);
}

// Round 4
// 1198.983 us; speedup vs baseline: 1.8289x; 1.0844x over previous
//
#include <hip/hip_runtime.h>

// MaxUnpooling2D scatter-add, bucketed radix-partition, round 4 (R3 + fix).
//
// out[mask[i] + (i & ~(FLAT_IN-1))] += updates[i];  rest of out = 0.
//
// R2: p3_place wrote 931 MB for a 268 MB pairs array (3.4x amplification:
// 46 B runs per block-bucket + 46 MB of open partial lines per XCD vs 4 MB
// L2). R3/R4: CHUNK 16K -> 128K so each block-bucket run is ~372 B (~6 full
// lines), open-line set ~5.8 MB/XCD -> L2 write-combining works.
// R4 fix: __builtin_nontemporal_store needs a NATIVE vector type, not
// HIP_vector_type<float,4> -> use ext_vector_type(4) alias.

typedef float floatx4 __attribute__((ext_vector_type(4)));

constexpr int FLAT_IN   = 1 << 22;               // 4,194,304
constexpr int N_ELEMS   = 8 * FLAT_IN;           // 33,554,432
constexpr int OUT_WIN   = 7 * FLAT_IN + (1 << 24); // 46,137,344
constexpr int OUT_TOTAL = 134217728;
constexpr int BKT_SHIFT = 14;
constexpr int BKT_SIZE  = 1 << BKT_SHIFT;        // 16,384 floats = 64 KB
constexpr int NB        = OUT_WIN >> BKT_SHIFT;  // 2816 = 11*256
constexpr int PBLOCK    = 1024;                  // threads, partition kernels
constexpr int CHUNK     = 131072;                // elems per partition block
constexpr int NBLK      = N_ELEMS / CHUNK;       // 256
constexpr int ITERS     = CHUNK / (4 * PBLOCK);  // 32
constexpr int SEGS      = 8;
constexpr int SEG_ROWS  = NBLK / SEGS;           // 32

// ---- workspace layout (bytes) ----
constexpr size_t WS_PAIRS  = 0;                                  // int2[N_ELEMS] = 268,435,456
constexpr size_t WS_HIST   = 268435456;                          // int[NBLK*NB] = 2,883,584
constexpr size_t WS_SEGSUM = WS_HIST + (size_t)NBLK * NB * 4;    // int[SEGS*NB]
constexpr size_t WS_BBASE  = WS_SEGSUM + (size_t)SEGS * NB * 4;  // int[NB+1]
constexpr size_t WS_NEEDED = WS_BBASE + (size_t)(NB + 1) * 4;

// ---------------- K0: zero a float4 range (nontemporal) ----------------
__global__ __launch_bounds__(256) void zero_kernel(floatx4* __restrict__ p, int n4) {
  int i = blockIdx.x * 256 + threadIdx.x;
  int stride = gridDim.x * 256;
  floatx4 z = {0.f, 0.f, 0.f, 0.f};
  for (; i < n4; i += stride) __builtin_nontemporal_store(z, p + i);
}

// ---------------- K1: per-block bucket histogram ----------------
__global__ __launch_bounds__(PBLOCK) void p1_hist(const int4* __restrict__ mask4,
                                                  int* __restrict__ hist) {
  __shared__ int cnt[NB];
  const int blk = blockIdx.x, tid = threadIdx.x;
  for (int j = tid; j < NB; j += PBLOCK) cnt[j] = 0;
  __syncthreads();
  const int base4 = blk * (CHUNK / 4);
  const int boff = (blk * CHUNK) & ~(FLAT_IN - 1);  // block-uniform batch offset
  #pragma unroll 4
  for (int k = 0; k < ITERS; ++k) {
    int4 m = mask4[base4 + k * PBLOCK + tid];
    atomicAdd(&cnt[(m.x + boff) >> BKT_SHIFT], 1);
    atomicAdd(&cnt[(m.y + boff) >> BKT_SHIFT], 1);
    atomicAdd(&cnt[(m.z + boff) >> BKT_SHIFT], 1);
    atomicAdd(&cnt[(m.w + boff) >> BKT_SHIFT], 1);
  }
  __syncthreads();
  for (int j = tid; j < NB; j += PBLOCK) hist[blk * NB + j] = cnt[j];
}

// ---------------- K2a: segment sums over block rows ----------------
__global__ __launch_bounds__(256) void p2_segsum(const int* __restrict__ hist,
                                                 int* __restrict__ segsum) {
  int b = blockIdx.x * 256 + threadIdx.x;
  int seg = blockIdx.y;
  const int* p = hist + (size_t)(seg * SEG_ROWS) * NB + b;
  int s = 0;
  #pragma unroll 4
  for (int k = 0; k < SEG_ROWS; ++k) s += p[(size_t)k * NB];
  segsum[seg * NB + b] = s;
}

// ---------------- K2b: bucket totals + exclusive scan -> bbase ----------------
__global__ __launch_bounds__(256) void p2_scan(const int* __restrict__ segsum,
                                               int* __restrict__ bbase) {
  __shared__ int tot[NB];
  __shared__ int partial[256];
  const int t = threadIdx.x;
  for (int j = t; j < NB; j += 256) {
    int s = 0;
    #pragma unroll
    for (int g = 0; g < SEGS; ++g) s += segsum[g * NB + j];
    tot[j] = s;
  }
  __syncthreads();
  int local = 0;
  #pragma unroll
  for (int k = 0; k < NB / 256; ++k) local += tot[t * (NB / 256) + k];
  partial[t] = local;
  __syncthreads();
  for (int off = 1; off < 256; off <<= 1) {
    int tmp = (t >= off) ? partial[t - off] : 0;
    __syncthreads();
    partial[t] += tmp;
    __syncthreads();
  }
  int run = partial[t] - local;
  #pragma unroll
  for (int k = 0; k < NB / 256; ++k) {
    int b = t * (NB / 256) + k;
    bbase[b] = run;
    run += tot[b];
  }
  if (t == 255) bbase[NB] = run;  // == N_ELEMS
}

// ---------------- K2c: expand hist in place to per-(block,bucket) offsets ----
__global__ __launch_bounds__(256) void p2_expand(int* __restrict__ hist,
                                                 const int* __restrict__ segsum) {
  int b = blockIdx.x * 256 + threadIdx.x;
  int seg = blockIdx.y;
  int run = 0;
  for (int g = 0; g < seg; ++g) run += segsum[g * NB + b];
  int* p = hist + (size_t)(seg * SEG_ROWS) * NB + b;
  for (int k = 0; k < SEG_ROWS; ++k) {
    int v = p[(size_t)k * NB];
    p[(size_t)k * NB] = run;
    run += v;
  }
}

// ---------------- K3: place pairs into bucket-sorted order ----------------
__global__ __launch_bounds__(PBLOCK) void p3_place(const int4* __restrict__ mask4,
                                                   const float4* __restrict__ upd4,
                                                   const int* __restrict__ hist,
                                                   const int* __restrict__ bbase,
                                                   int2* __restrict__ pairs) {
  __shared__ int cnt[NB];
  __shared__ int rowbase[NB];  // absolute start for this (block,bucket)
  const int blk = blockIdx.x, tid = threadIdx.x;
  for (int j = tid; j < NB; j += PBLOCK) {
    cnt[j] = 0;
    rowbase[j] = bbase[j] + hist[blk * NB + j];
  }
  __syncthreads();
  const int base4 = blk * (CHUNK / 4);
  const int boff = (blk * CHUNK) & ~(FLAT_IN - 1);
  #pragma unroll 2
  for (int k = 0; k < ITERS; ++k) {
    int j4 = base4 + k * PBLOCK + tid;
    int4 m = mask4[j4];
    float4 u = upd4[j4];
    {
      int idx = m.x + boff; int b = idx >> BKT_SHIFT;
      int r = atomicAdd(&cnt[b], 1);
      pairs[rowbase[b] + r] = make_int2(idx, __float_as_int(u.x));
    }
    {
      int idx = m.y + boff; int b = idx >> BKT_SHIFT;
      int r = atomicAdd(&cnt[b], 1);
      pairs[rowbase[b] + r] = make_int2(idx, __float_as_int(u.y));
    }
    {
      int idx = m.z + boff; int b = idx >> BKT_SHIFT;
      int r = atomicAdd(&cnt[b], 1);
      pairs[rowbase[b] + r] = make_int2(idx, __float_as_int(u.z));
    }
    {
      int idx = m.w + boff; int b = idx >> BKT_SHIFT;
      int r = atomicAdd(&cnt[b], 1);
      pairs[rowbase[b] + r] = make_int2(idx, __float_as_int(u.w));
    }
  }
}

// ---------------- K4: apply one bucket via LDS, store window ----------------
__global__ __launch_bounds__(256) void p4_apply(const int2* __restrict__ pairs,
                                                const int* __restrict__ bbase,
                                                float* __restrict__ out) {
  __shared__ float win[BKT_SIZE];  // 64 KB -> 2 blocks/CU
  const int bkt = blockIdx.x, tid = threadIdx.x;
  floatx4* w4 = (floatx4*)win;
  floatx4 z = {0.f, 0.f, 0.f, 0.f};
  #pragma unroll
  for (int k = 0; k < BKT_SIZE / 1024; ++k) w4[k * 256 + tid] = z;
  __syncthreads();
  const int s = bbase[bkt], e = bbase[bkt + 1];
  const int s4 = (s + 1) & ~1;  // first even pair index
  if ((s & 1) && s < e && tid == 0) {
    int2 p = pairs[s];
    atomicAdd(&win[p.x & (BKT_SIZE - 1)], __int_as_float(p.y));
  }
  const int n2 = (e > s4) ? ((e - s4) >> 1) : 0;  // # of 2-pair groups
  const int4* pv = (const int4*)(pairs + s4);     // 16B-aligned
  for (int i = tid; i < n2; i += 256) {
    int4 q = pv[i];
    atomicAdd(&win[q.x & (BKT_SIZE - 1)], __int_as_float(q.y));
    atomicAdd(&win[q.z & (BKT_SIZE - 1)], __int_as_float(q.w));
  }
  if ((e > s4) && ((e - s4) & 1) && tid == 0) {
    int2 p = pairs[e - 1];
    atomicAdd(&win[p.x & (BKT_SIZE - 1)], __int_as_float(p.y));
  }
  __syncthreads();
  floatx4* o4 = (floatx4*)(out + (size_t)bkt * BKT_SIZE);
  #pragma unroll
  for (int k = 0; k < BKT_SIZE / 1024; ++k)
    __builtin_nontemporal_store(w4[k * 256 + tid], o4 + k * 256 + tid);
}

// ---------------- fallback: R1 atomic scatter ----------------
__global__ __launch_bounds__(256) void scatter_add4_kernel(
    const float4* __restrict__ upd4, const int4* __restrict__ msk4,
    float* __restrict__ out, int n4) {
  int j = blockIdx.x * blockDim.x + threadIdx.x;
  if (j >= n4) return;
  float4 u = upd4[j];
  int4 m = msk4[j];
  int base = (j * 4) & ~(FLAT_IN - 1);
  unsafeAtomicAdd(out + (base + m.x), u.x);
  unsafeAtomicAdd(out + (base + m.y), u.y);
  unsafeAtomicAdd(out + (base + m.z), u.z);
  unsafeAtomicAdd(out + (base + m.w), u.w);
}

extern "C" void kernel_launch(void* const* d_in, const int* in_sizes, int n_in,
                              void* d_out, int out_size, void* d_ws, size_t ws_size,
                              hipStream_t stream) {
  const float* updates = (const float*)d_in[0];
  const int*   mask    = (const int*)d_in[1];
  float*       out     = (float*)d_out;
  const int n = in_sizes[0];

  const bool fast = (n == N_ELEMS) && (out_size == OUT_TOTAL) && (ws_size >= WS_NEEDED);

  if (!fast) {
    int n4z = out_size / 4;
    zero_kernel<<<(n4z + 2047) / 2048, 256, 0, stream>>>((floatx4*)d_out, n4z);
    int n4 = n / 4;
    scatter_add4_kernel<<<(n4 + 255) / 256, 256, 0, stream>>>(
        (const float4*)updates, (const int4*)mask, out, n4);
    return;
  }

  char* ws = (char*)d_ws;
  int2* pairs  = (int2*)(ws + WS_PAIRS);
  int*  hist   = (int*)(ws + WS_HIST);
  int*  segsum = (int*)(ws + WS_SEGSUM);
  int*  bbase  = (int*)(ws + WS_BBASE);

  // zero the untouched tail of out: [OUT_WIN, OUT_TOTAL), 352 MB
  {
    int n4 = (OUT_TOTAL - OUT_WIN) / 4;  // 22,020,096
    zero_kernel<<<5376, 256, 0, stream>>>((floatx4*)(out + OUT_WIN), n4);
  }
  p1_hist<<<NBLK, PBLOCK, 0, stream>>>((const int4*)mask, hist);
  p2_segsum<<<dim3(NB / 256, SEGS), 256, 0, stream>>>(hist, segsum);
  p2_scan<<<1, 256, 0, stream>>>(segsum, bbase);
  p2_expand<<<dim3(NB / 256, SEGS), 256, 0, stream>>>(hist, segsum);
  p3_place<<<NBLK, PBLOCK, 0, stream>>>((const int4*)mask, (const float4*)updates,
                                        hist, bbase, pairs);
  p4_apply<<<NB, 256, 0, stream>>>(pairs, bbase, out);
}